// Round 4
// baseline (731.797 us; speedup 1.0000x reference)
//
#include <hip/hip_runtime.h>

typedef _Float16 half8 __attribute__((ext_vector_type(8)));
typedef float f32x4 __attribute__((ext_vector_type(4)));

// ---------------- workspace layout (int indices) ----------------
#define WS_CUR(e)    (160 + (e) * 32)    // per-element scatter cursors (final = count)
#define WS_PERM      512                 // perm: 4 regions of Nr ints; idxs: 4 more regions
// w1h (fp16 chunk layout, 4*1024 chunks * 16B = 64 KB) after perm+idxs, 16B-aligned

// ---------------- pass 1: scatter atoms into per-element regions + W1 fp16 convert ----
// No counting pass needed: each element has a private N-sized region; blocks reserve
// chunks via one atomic per element per block. Also pre-scatters idx_m so the main
// kernel's molecule ids are a coalesced load (no dependent gather).
__global__ void k_scatter(const int* __restrict__ zidx, const int* __restrict__ idx_m,
                          int N, int Nr, int* __restrict__ ws,
                          const float* __restrict__ W1, _Float16* __restrict__ w1h) {
  // first 16 blocks convert W1 (f32 [e][d=128][h=64]) into chunked fp16:
  // chunk cg: halfs[j] = W1[e][d0+j][h], h = nt*16+(l2&15), d0 = kt*32+(l2>>4)*8
  if (blockIdx.x < 16) {
    const int cg = blockIdx.x * 256 + threadIdx.x;   // 0..4095
    const int e = cg >> 10, ch = cg & 1023;
    const int kt = ch >> 8, nt = (ch >> 6) & 3, l2 = ch & 63;
    const int h = nt * 16 + (l2 & 15);
    const int d0 = kt * 32 + (l2 >> 4) * 8;
    const float* w1e = W1 + (size_t)e * 8192;
    half8 hv;
#pragma unroll
    for (int j = 0; j < 8; ++j) hv[j] = (_Float16)w1e[(d0 + j) * 64 + h];
    *(half8*)&w1h[(size_t)cg * 8] = hv;
  }
  __shared__ int cnts[4][4][4];  // [iter][wave][e]
  __shared__ int pb[4][4][4];    // region-relative write base per (iter,wave,e)
  const int tid = threadIdx.x, lane = tid & 63, wave = tid >> 6;
  const int base = blockIdx.x * 1024;
  int zz[4], iv[4];
#pragma unroll
  for (int it = 0; it < 4; ++it) {
    const int i = base + it * 256 + tid;
    zz[it] = (i < N) ? zidx[i] : -1;
    iv[it] = (i < N) ? idx_m[i] : 0;
#pragma unroll
    for (int e = 0; e < 4; ++e) {
      unsigned long long m = __ballot(zz[it] == e);
      if (lane == 0) cnts[it][wave][e] = __popcll(m);
    }
  }
  __syncthreads();
  if (tid < 4) {
    const int e = tid;
    int tot = 0;
#pragma unroll
    for (int it = 0; it < 4; ++it)
#pragma unroll
      for (int w = 0; w < 4; ++w) tot += cnts[it][w][e];
    int run = tot ? atomicAdd(&ws[WS_CUR(e)], tot) : 0;
#pragma unroll
    for (int it = 0; it < 4; ++it)
#pragma unroll
      for (int w = 0; w < 4; ++w) { pb[it][w][e] = run; run += cnts[it][w][e]; }
  }
  __syncthreads();
  const unsigned long long below = (1ull << lane) - 1ull;
#pragma unroll
  for (int it = 0; it < 4; ++it) {
    const int z = zz[it];
    const unsigned long long m0 = __ballot(z == 0);
    const unsigned long long m1 = __ballot(z == 1);
    const unsigned long long m2 = __ballot(z == 2);
    const unsigned long long m3 = __ballot(z == 3);
    if (z >= 0) {
      const unsigned long long me = (z == 0) ? m0 : (z == 1) ? m1 : (z == 2) ? m2 : m3;
      const int r = __popcll(me & below);
      const int dst = WS_PERM + z * Nr + pb[it][wave][z] + r;
      ws[dst] = base + it * 256 + tid;        // perm
      ws[dst + 4 * Nr] = iv[it];              // pre-scattered molecule id
    }
  }
}

// ---------------- main: 1024 atoms/block, 3-stage rolling pipeline ----------------
#define PRE(g_, pv_, iv_) do {                                                  \
    const int pos_ = bstart + (g_) * 64 + wave * 16 + c;                        \
    if (pos_ < fillE) { pv_ = permE[pos_]; iv_ = idxsE[pos_]; }                 \
    else { pv_ = -1; iv_ = 0; }                                                 \
  } while (0)

#define LOADF(dst, pv_) do {                                                    \
    const int ap_ = (pv_);                                                      \
    const f32x4* rp_ = (const f32x4*)(x + (long)(ap_ < 0 ? 0 : ap_) * 128);     \
    _Pragma("unroll")                                                           \
    for (int kt = 0; kt < 4; ++kt) {                                            \
      f32x4 u0 = rp_[kt * 8 + q * 2];                                           \
      f32x4 u1 = rp_[kt * 8 + q * 2 + 1];                                       \
      half8 a;                                                                  \
      a[0] = (_Float16)u0[0]; a[1] = (_Float16)u0[1];                           \
      a[2] = (_Float16)u0[2]; a[3] = (_Float16)u0[3];                           \
      a[4] = (_Float16)u1[0]; a[5] = (_Float16)u1[1];                           \
      a[6] = (_Float16)u1[2]; a[7] = (_Float16)u1[3];                           \
      dst[kt] = a;                                                              \
    }                                                                           \
  } while (0)

#define COMPUTE(af_, apl_, ivl_) do {                                           \
    f32x4 acc[4];                                                               \
    _Pragma("unroll")                                                           \
    for (int nt = 0; nt < 4; ++nt) acc[nt] = (f32x4){0.f, 0.f, 0.f, 0.f};       \
    _Pragma("unroll")                                                           \
    for (int kt = 0; kt < 4; ++kt)                                              \
      _Pragma("unroll")                                                         \
      for (int nt = 0; nt < 4; ++nt) {                                          \
        half8 bf = *(const half8*)&w1t[((kt * 4 + nt) * 64 + lane) * 8];        \
        acc[nt] = __builtin_amdgcn_mfma_f32_16x16x32_f16(af_[kt], bf, acc[nt], 0, 0, 0); \
      }                                                                         \
    float sv[4];                                                                \
    _Pragma("unroll")                                                           \
    for (int i = 0; i < 4; ++i) {                                               \
      float s = 0.0f;                                                           \
      _Pragma("unroll")                                                         \
      for (int nt = 0; nt < 4; ++nt) {                                          \
        float tv = acc[nt][i] + b1v[nt];                                        \
        float hsp = __logf(1.0f + __expf(tv)) - 0.69314718056f;                 \
        s = fmaf(hsp, w2v[nt], s);                                              \
      }                                                                         \
      s += __shfl_xor(s, 1);                                                    \
      s += __shfl_xor(s, 2);                                                    \
      s += __shfl_xor(s, 4);                                                    \
      s += __shfl_xor(s, 8);                                                    \
      sv[i] = s;                                                                \
    }                                                                           \
    /* transpose: lane l<16 gets slot l's sum */                                \
    const int srcl = (lane >> 2) << 4;                                          \
    float t0 = __shfl(sv[0], srcl);                                             \
    float t1 = __shfl(sv[1], srcl);                                             \
    float t2 = __shfl(sv[2], srcl);                                             \
    float t3 = __shfl(sv[3], srcl);                                             \
    const int r3 = lane & 3;                                                    \
    float val = (r3 == 0) ? t0 : (r3 == 1) ? t1 : (r3 == 2) ? t2 : t3;          \
    val = ((apl_) >= 0) ? val + b2e : 0.0f;                                     \
    const int ivp = __shfl_up((ivl_), 1);                                       \
    const int head = (lane == 0) || ((ivl_) != ivp);                            \
    int flg = head;                                                             \
    float v = val;                                                              \
    _Pragma("unroll")                                                           \
    for (int d = 1; d < 16; d <<= 1) {                                          \
      float v2 = __shfl_up(v, d);                                               \
      int f2 = __shfl_up(flg, d);                                               \
      if (lane >= d && !flg) v += v2;                                           \
      if (lane >= d) flg |= f2;                                                 \
    }                                                                           \
    const int nh = __shfl_down(head, 1);                                        \
    if (lane < 16 && ((lane == 15) || nh)) atomicAdd(&y[(ivl_)], v);            \
  } while (0)

__global__ __launch_bounds__(256, 4)
void elemental_main(const float* __restrict__ x,
                    const _Float16* __restrict__ w1h,
                    const float* __restrict__ b1,
                    const float* __restrict__ W2,
                    const float* __restrict__ b2,
                    const int* __restrict__ ws,
                    float* __restrict__ y,
                    int Nr, int bpe) {
  __shared__ _Float16 w1t[8192];  // 16 KB

  const int e = blockIdx.x / bpe;
  const int bi = blockIdx.x - e * bpe;
  const int fillE = ws[WS_CUR(e)];
  const int bstart = bi << 10;
  if (bstart >= fillE) return;
  const int* permE = ws + WS_PERM + (size_t)e * Nr;
  const int* idxsE = permE + 4 * (size_t)Nr;

  // stage W1h[e] -> LDS (coalesced b128)
  const int tid = threadIdx.x;
  const half8* src = (const half8*)w1h + (size_t)e * 1024;
#pragma unroll
  for (int it = 0; it < 4; ++it) {
    const int kk = it * 256 + tid;
    *(half8*)&w1t[kk * 8] = src[kk];
  }

  const int lane = tid & 63;
  const int wave = tid >> 6;
  const int c = lane & 15;
  const int q = lane >> 4;

  float b1v[4], w2v[4];
#pragma unroll
  for (int nt = 0; nt < 4; ++nt) {
    b1v[nt] = b1[e * 64 + nt * 16 + c];
    w2v[nt] = W2[e * 64 + nt * 16 + c];
  }
  const float b2e = b2[e];

  // 3-stage rolling pipeline over 16 groups of 64 atoms:
  //   PRE (perm+idx, distance 2) -> LOADF (x rows, distance 1) -> COMPUTE
  int pv0, iv0, pv1, iv1;
  half8 af0[4], af1[4];
  PRE(0, pv0, iv0);
  PRE(1, pv1, iv1);
  LOADF(af0, pv0);
  __syncthreads();

#pragma unroll 1
  for (int g = 0; g < 16; g += 2) {
    // even: compute g (af0/pv0), load g+1 (af1/pv1), prefetch g+2 -> (pv0,iv0)
    LOADF(af1, pv1);
    {
      const int apl = pv0, ivl = iv0;
      if (g + 2 < 16) PRE(g + 2, pv0, iv0);
      COMPUTE(af0, apl, ivl);
    }
    // odd: compute g+1 (af1/pv1), load g+2 (af0/pv0), prefetch g+3 -> (pv1,iv1)
    if (g + 2 < 16) LOADF(af0, pv0);
    {
      const int apl = pv1, ivl = iv1;
      if (g + 3 < 16) PRE(g + 3, pv1, iv1);
      COMPUTE(af1, apl, ivl);
    }
  }
}

// ---------------- fallback: verified all-elements kernel ----------------
#define LDSROW_OLD 136

__global__ __launch_bounds__(256, 2)
void elemental_atomwise_kernel(const float* __restrict__ x,
                               const int* __restrict__ zidx,
                               const int* __restrict__ idx_m,
                               const float* __restrict__ W1,
                               const float* __restrict__ b1,
                               const float* __restrict__ W2,
                               const float* __restrict__ b2,
                               float* __restrict__ y,
                               int N) {
  extern __shared__ _Float16 w1t[];
#pragma unroll
  for (int it = 0; it < 32; ++it) {
    int idx4 = threadIdx.x + it * 256;
    f32x4 v = ((const f32x4*)W1)[idx4];
    int lin = idx4 << 2;
    int d = (lin >> 6) & 127;
    int ee = lin >> 13;
    int h = lin & 63;
    int n = ee * 64 + h;
#pragma unroll
    for (int j = 0; j < 4; ++j)
      w1t[(n + j) * LDSROW_OLD + d] = (_Float16)v[j];
  }
  __syncthreads();

  const int lane = threadIdx.x & 63;
  const int wave = threadIdx.x >> 6;
  const int c = lane & 15;
  const int q = lane >> 4;
  const long tile = (long)blockIdx.x * 4 + wave;
  const long base = tile * 64;
  if (base >= N) return;

  int ameta = (base + lane < N) ? (int)(base + lane) : (N - 1);
  const int zvec = zidx[ameta];
  const int ivec = idx_m[ameta];

  half8 af[4][4];
#pragma unroll
  for (int mt = 0; mt < 4; ++mt) {
    long row = base + mt * 16 + c;
    if (row >= N) row = N - 1;
    const f32x4* rp = (const f32x4*)(x + row * 128);
#pragma unroll
    for (int kt = 0; kt < 4; ++kt) {
      f32x4 u0 = rp[kt * 8 + q * 2];
      f32x4 u1 = rp[kt * 8 + q * 2 + 1];
      half8 a;
      a[0] = (_Float16)u0[0]; a[1] = (_Float16)u0[1];
      a[2] = (_Float16)u0[2]; a[3] = (_Float16)u0[3];
      a[4] = (_Float16)u1[0]; a[5] = (_Float16)u1[1];
      a[6] = (_Float16)u1[2]; a[7] = (_Float16)u1[3];
      af[mt][kt] = a;
    }
  }

#pragma unroll
  for (int e = 0; e < 4; ++e) {
    f32x4 acc[4][4];
#pragma unroll
    for (int mt = 0; mt < 4; ++mt)
#pragma unroll
      for (int nt = 0; nt < 4; ++nt)
        acc[mt][nt] = (f32x4){0.f, 0.f, 0.f, 0.f};

#pragma unroll
    for (int kt = 0; kt < 4; ++kt) {
#pragma unroll
      for (int nt = 0; nt < 4; ++nt) {
        half8 bf = *(const half8*)&w1t[(e * 64 + nt * 16 + c) * LDSROW_OLD + kt * 32 + q * 8];
#pragma unroll
        for (int mt = 0; mt < 4; ++mt)
          acc[mt][nt] = __builtin_amdgcn_mfma_f32_16x16x32_f16(af[mt][kt], bf, acc[mt][nt], 0, 0, 0);
      }
    }

    float b1v[4], w2v[4];
#pragma unroll
    for (int nt = 0; nt < 4; ++nt) {
      b1v[nt] = b1[e * 64 + nt * 16 + c];
      w2v[nt] = W2[e * 64 + nt * 16 + c];
    }
    const float b2e = b2[e];
#pragma unroll
    for (int mt = 0; mt < 4; ++mt) {
#pragma unroll
      for (int i = 0; i < 4; ++i) {
        float s = 0.0f;
#pragma unroll
        for (int nt = 0; nt < 4; ++nt) {
          float tv = acc[mt][nt][i] + b1v[nt];
          float hsp = __logf(1.0f + __expf(tv)) - 0.69314718056f;
          s = fmaf(hsp, w2v[nt], s);
        }
        s += __shfl_xor(s, 1);
        s += __shfl_xor(s, 2);
        s += __shfl_xor(s, 4);
        s += __shfl_xor(s, 8);
        int mloc = mt * 16 + q * 4 + i;
        int zm = __shfl(zvec, mloc);
        int im = __shfl(ivec, mloc);
        if (c == 0 && zm == e && base + mloc < N)
          atomicAdd(&y[im], s + b2e);
      }
    }
  }
}

extern "C" void kernel_launch(void* const* d_in, const int* in_sizes, int n_in,
                              void* d_out, int out_size, void* d_ws, size_t ws_size,
                              hipStream_t stream) {
  const float* x = (const float*)d_in[0];
  const int* zidx = (const int*)d_in[1];
  const int* idx_m = (const int*)d_in[2];
  const float* W1 = (const float*)d_in[3];
  const float* b1 = (const float*)d_in[4];
  const float* W2 = (const float*)d_in[5];
  const float* b2 = (const float*)d_in[6];
  float* y = (float*)d_out;

  const int N = in_sizes[0] / 128;

  hipMemsetAsync(d_out, 0, (size_t)out_size * sizeof(float), stream);

  const int bpe = (N + 1023) >> 10;                 // blocks per element region
  const int Nr = bpe << 10;                         // region size (ints)
  const size_t w1h_off = ((size_t)512 + 8 * (size_t)Nr + 3) & ~(size_t)3;
  const size_t ws_need = w1h_off * sizeof(int) + 65536;
  if (ws_size >= ws_need) {
    int* ws = (int*)d_ws;
    _Float16* w1h = (_Float16*)(ws + w1h_off);
    hipMemsetAsync(d_ws, 0, 2048, stream);          // zero cursors
    const int nbs = bpe < 16 ? 16 : bpe;
    k_scatter<<<nbs, 256, 0, stream>>>(zidx, idx_m, N, Nr, ws, W1, w1h);
    elemental_main<<<4 * bpe, 256, 0, stream>>>(x, w1h, b1, W2, b2, ws, y, Nr, bpe);
  } else {
    const int tiles = (N + 63) / 64;
    const int blocks = (tiles + 3) / 4;
    const size_t lds_bytes = 256 * LDSROW_OLD * sizeof(_Float16);
    elemental_atomwise_kernel<<<blocks, 256, lds_bytes, stream>>>(
        x, zidx, idx_m, W1, b1, W2, b2, y, N);
  }
}